// Round 14
// baseline (457.299 us; speedup 1.0000x reference)
//
#include <hip/hip_runtime.h>

#define ALPHA_F 0.1f
#define EPS_F   1e-5f
#define INV256  0.00390625f

typedef float    f32x4 __attribute__((ext_vector_type(4)));
typedef _Float16 h16x8 __attribute__((ext_vector_type(8)));
typedef int      i32x3 __attribute__((ext_vector_type(3)));

__device__ __forceinline__ void gll16(const void* g, void* l)
{
    __builtin_amdgcn_global_load_lds(
        (const __attribute__((address_space(1))) void*)g,
        (__attribute__((address_space(3))) void*)l, 16, 0, 0);
}

// padded count per node: self-loop + edges, rounded up to multiple of 8
__device__ __forceinline__ int pad_cnt(int d) { return (d + 8) & ~7; }

// ---- 12-bit fixed-point (scale 1/256) pack/unpack: 8 feats <-> 3 dwords ----
__device__ __forceinline__ void pack12(const float* o, unsigned* d)
{
    int q[8];
#pragma unroll
    for (int j = 0; j < 8; ++j) {
        float x = fminf(fmaxf(o[j] * 256.f, -2047.f), 2047.f);
        q[j] = (int)lrintf(x) & 0xFFF;
    }
    d[0] = (unsigned)q[0] | ((unsigned)q[1] << 12) | ((unsigned)q[2] << 24);
    d[1] = ((unsigned)q[2] >> 8) | ((unsigned)q[3] << 4)
         | ((unsigned)q[4] << 16) | ((unsigned)q[5] << 28);
    d[2] = ((unsigned)q[5] >> 4) | ((unsigned)q[6] << 8) | ((unsigned)q[7] << 20);
}

__device__ __forceinline__ void unpack12(unsigned d0, unsigned d1, unsigned d2,
                                         float* f)
{
    f[0] = (float)(((int)(d0 << 20)) >> 20);
    f[1] = (float)(((int)(d0 << 8))  >> 20);
    unsigned u2 = (d0 >> 24) | (d1 << 8);
    f[2] = (float)(((int)(u2 << 20)) >> 20);
    f[3] = (float)(((int)(d1 << 16)) >> 20);
    f[4] = (float)(((int)(d1 << 4))  >> 20);
    unsigned u5 = (d1 >> 28) | (d2 << 4);
    f[5] = (float)(((int)(u5 << 20)) >> 20);
    f[6] = (float)(((int)(d2 << 12)) >> 20);
    f[7] = (float)(((int)d2) >> 20);
}

// h0h [N][128] fp16 -> packed q rows [N][48] dwords
__global__ void pack_rows(const _Float16* __restrict__ src,
                          unsigned* __restrict__ dst, int total)
{
    int idx = blockIdx.x * 256 + threadIdx.x;   // one per (row, 8-feat chunk)
    if (idx < total) {
        h16x8 v = *(const h16x8*)(src + (size_t)idx * 8);
        float o[8];
#pragma unroll
        for (int j = 0; j < 8; ++j) o[j] = (float)v[j];
        unsigned d[3];
        pack12(o, d);
        unsigned* p = dst + (size_t)idx * 3;
        p[0] = d[0]; p[1] = d[1]; p[2] = d[2];
    }
}

// ---------------------------------------------------------------------------
// W [K x 128] fp32 -> staging-interleaved fp16 layout
// ---------------------------------------------------------------------------
__global__ void convert_wstg(const float* __restrict__ W,
                             _Float16* __restrict__ Wstg, int K)
{
    int idx = blockIdx.x * 256 + threadIdx.x;
    if (idx < K * 128) {
        int k = idx >> 7, n = idx & 127;
        int i = k >> 5, kg = (k >> 3) & 3, j = k & 7;
        Wstg[(size_t)i * 4096 + (kg * 128 + n) * 8 + j] = (_Float16)W[idx];
    }
}

// ---------------------------------------------------------------------------
// out[M,128] = BN( act(A[M,K] @ W + bias) ) — unchanged m97-style GEMM.
// ---------------------------------------------------------------------------
template<bool A_HALF, bool OUT_HALF>
__global__ __launch_bounds__(256) void gemm_stage_bn(
    const void* __restrict__ Av,
    const _Float16* __restrict__ Wstg,
    const float* __restrict__ bias,
    const float* __restrict__ gamma, const float* __restrict__ beta,
    const float* __restrict__ mean,  const float* __restrict__ var,
    void* __restrict__ outv, int M, int K, int do_relu)
{
    __shared__ __align__(16) char Abuf[2][8192];
    __shared__ __align__(16) char Wbuf[2][8192];

    const int t   = threadIdx.x;
    const int w   = t >> 6;
    const int l   = t & 63;
    const int l15 = l & 15;
    const int lk  = l >> 4;
    const int bm  = blockIdx.x * 64;
    const int nk  = K >> 5;
    const int row = w * 16 + l15;

    f32x4 acc[8];
#pragma unroll
    for (int f = 0; f < 8; ++f) acc[f] = (f32x4){0.f, 0.f, 0.f, 0.f};

    auto stage = [&](int buf, int i) {
        const char* wsrc = (const char*)Wstg + (size_t)i * 8192;
#pragma unroll
        for (int c = 0; c < 2; ++c) {
            const int base = w * 128 + c * 64;
            gll16(wsrc + (size_t)(base + l) * 16, &Wbuf[buf][base * 16]);
        }
        if (A_HALF) {
            const int base = w * 64;
            const int sl   = base + l;
            const int r    = sl >> 2;
            const int ch   = (sl & 3) ^ (r & 3);
            int gr = bm + r; gr = (gr < M) ? gr : (M - 1);
            const char* src = (const char*)Av + ((size_t)gr * K + i * 32) * 2
                              + (size_t)ch * 16;
            gll16(src, &Abuf[buf][base * 16]);
        } else {
#pragma unroll
            for (int c = 0; c < 2; ++c) {
                const int base = w * 128 + c * 64;
                const int sl   = base + l;
                const int r    = sl >> 3;
                const int ch   = (sl & 7) ^ (r & 7);
                int gr = bm + r; gr = (gr < M) ? gr : (M - 1);
                const char* src = (const char*)Av + ((size_t)gr * K + i * 32) * 4
                                  + (size_t)ch * 16;
                gll16(src, &Abuf[buf][base * 16]);
            }
        }
    };

    auto compute = [&](int buf) {
        h16x8 a;
        if (A_HALF) {
            a = *(const h16x8*)&Abuf[buf][(row * 4 + (lk ^ (row & 3))) * 16];
        } else {
            f32x4 a0 = *(const f32x4*)&Abuf[buf][(row * 8 + ((2 * lk)     ^ (row & 7))) * 16];
            f32x4 a1 = *(const f32x4*)&Abuf[buf][(row * 8 + ((2 * lk + 1) ^ (row & 7))) * 16];
#pragma unroll
            for (int j = 0; j < 4; ++j) {
                a[j]     = (_Float16)a0[j];
                a[4 + j] = (_Float16)a1[j];
            }
        }
#pragma unroll
        for (int f = 0; f < 8; ++f) {
            h16x8 b = *(const h16x8*)&Wbuf[buf][(lk * 128 + f * 16 + l15) * 16];
            acc[f] = __builtin_amdgcn_mfma_f32_16x16x32_f16(a, b, acc[f], 0, 0, 0);
        }
    };

    stage(0, 0);
    for (int i = 0; i < nk; ++i) {
        __syncthreads();
        if (i + 1 < nk) stage((i + 1) & 1, i + 1);
        compute(i & 1);
    }

#pragma unroll
    for (int f = 0; f < 8; ++f) {
        const int col = f * 16 + l15;
        float s  = gamma[col] * rsqrtf(var[col] + EPS_F);
        float sh = beta[col] - mean[col] * s;
        float bb = bias[col];
#pragma unroll
        for (int rr = 0; rr < 4; ++rr) {
            int rg = bm + w * 16 + lk * 4 + rr;
            if (rg < M) {
                float v = acc[f][rr] + bb;
                if (do_relu) v = fmaxf(v, 0.f);
                v = v * s + sh;
                if (OUT_HALF) ((_Float16*)outv)[(size_t)rg * 128 + col] = (_Float16)v;
                else          ((float*)outv)[(size_t)rg * 128 + col]    = v;
            }
        }
    }
}

// ---------------------------------------------------------------------------
// Graph preprocessing (per launch). CSR entries are PACKED int2 {src, val}.
// ---------------------------------------------------------------------------
__global__ void count_deg(const int* __restrict__ dst, int E, int* __restrict__ deg)
{
    int e = blockIdx.x * 256 + threadIdx.x;
    if (e < E) atomicAdd(&deg[dst[e]], 1);
}

__global__ __launch_bounds__(256) void scan_block_sums(
    const int* __restrict__ deg, int* __restrict__ bsum, int N)
{
    __shared__ int sh[256];
    const int t  = threadIdx.x;
    const int i0 = blockIdx.x * 1024 + t * 4;
    int s = 0;
    if (i0 + 3 < N) {
        int4 d4 = *(const int4*)(deg + i0);
        s = pad_cnt(d4.x) + pad_cnt(d4.y) + pad_cnt(d4.z) + pad_cnt(d4.w);
    } else {
#pragma unroll
        for (int j = 0; j < 4; ++j)
            if (i0 + j < N) s += pad_cnt(deg[i0 + j]);
    }
    sh[t] = s;
    __syncthreads();
#pragma unroll
    for (int d = 128; d > 0; d >>= 1) {
        if (t < d) sh[t] += sh[t + d];
        __syncthreads();
    }
    if (t == 0) bsum[blockIdx.x] = sh[0];
}

__global__ __launch_bounds__(256) void scan_offsets(
    const int* __restrict__ deg, const int* __restrict__ bsum,
    int* __restrict__ offs, int* __restrict__ cursor,
    float* __restrict__ dinv, int N, int B)
{
    __shared__ int sh[256];
    __shared__ int sbase;
    const int b = blockIdx.x, t = threadIdx.x;

    int v = (t < b && t < B) ? bsum[t] : 0;
    sh[t] = v;
    __syncthreads();
#pragma unroll
    for (int d = 128; d > 0; d >>= 1) {
        if (t < d) sh[t] += sh[t + d];
        __syncthreads();
    }
    if (t == 0) sbase = sh[0];
    __syncthreads();

    const int i0 = b * 1024 + t * 4;
    int c[4], s = 0;
#pragma unroll
    for (int j = 0; j < 4; ++j) {
        int i = i0 + j;
        c[j] = (i < N) ? pad_cnt(deg[i]) : 0;
        s += c[j];
    }
    sh[t] = s;
    __syncthreads();
    for (int d = 1; d < 256; d <<= 1) {
        int o = (t >= d) ? sh[t - d] : 0;
        __syncthreads();
        sh[t] += o;
        __syncthreads();
    }
    int run = sbase + sh[t] - s;
#pragma unroll
    for (int j = 0; j < 4; ++j) {
        int i = i0 + j;
        if (i < N) {
            offs[i]   = run;
            cursor[i] = run;
            dinv[i]   = rsqrtf((float)(deg[i] + 1));
            run += c[j];
        }
    }
    if (b == B - 1 && t == 255) offs[N] = run;
}

__global__ void scatter_csr(const int* __restrict__ src, const int* __restrict__ dst,
                            int E, const float* __restrict__ dinv,
                            int* __restrict__ cursor, int2* __restrict__ csr)
{
    int e = blockIdx.x * 256 + threadIdx.x;
    if (e < E) {
        int s = src[e], d = dst[e];
        int pos = atomicAdd(&cursor[d], 1);
        csr[pos] = make_int2(s, __float_as_int(dinv[s] * dinv[d]));
    }
}

__global__ void fill_self_pad(const int* __restrict__ offs, const int* __restrict__ deg,
                              const float* __restrict__ dinv,
                              int2* __restrict__ csr, int N)
{
    int i = blockIdx.x * 256 + threadIdx.x;
    if (i < N) {
        int base = offs[i], d = deg[i], end = offs[i + 1];
        float di = dinv[i];
        csr[base + d] = make_int2(i, __float_as_int(di * di));
        for (int p = base + d + 1; p < end; ++p)
            csr[p] = make_int2(i, 0);
    }
}

// ---------------------------------------------------------------------------
// One APPNP step on 12-bit packed features: nxt = (1-a)*(A_hat @ cur) + a*h0.
// Packed row = 128 x 12 bit = 48 dwords = 192 B (3 x 64B sectors, aligned).
// Persistent waves (8192); four 16-lane groups; group g owns edges e+2g,
// e+2g+1; each lane loads dwordx3 (8 feats) per edge, unpacks, fp32 FMA.
// Teleport h0 read fp16; output packed (steps 0-8) or fp32 d_out (step 9).
// ---------------------------------------------------------------------------
#define NWAVES 8192

__global__ __launch_bounds__(256) void appnp_step_q(
    const unsigned* __restrict__ cur, const _Float16* __restrict__ h0,
    const int* __restrict__ offs, const int2* __restrict__ csr,
    unsigned* __restrict__ nxt, float* __restrict__ fout, int N)
{
    const int wv0  = __builtin_amdgcn_readfirstlane(
                        (int)((blockIdx.x * 256u + threadIdx.x) >> 6));
    const int lane = (int)(threadIdx.x & 63u);
    const int g    = lane >> 4;          // group 0..3
    const int sl   = lane & 15;          // sub-lane
    const int dw   = sl * 3;             // dword offset within packed row

    for (int i = wv0; i < N; i += NWAVES) {
        int e   = offs[i];
        int end = offs[i + 1];

        float acc[8];
#pragma unroll
        for (int j = 0; j < 8; ++j) acc[j] = 0.f;

        // stage first 8 edges: group g owns edges e+2g, e+2g+1
        int4  m = *(const int4*)(csr + e + 2 * g);
        i32x3 a = *(const i32x3*)(cur + (size_t)m.x * 48 + dw);
        i32x3 b = *(const i32x3*)(cur + (size_t)m.z * 48 + dw);

        for (e += 8; e < end; e += 8) {
            int4  m2 = *(const int4*)(csr + e + 2 * g);
            i32x3 a2 = *(const i32x3*)(cur + (size_t)m2.x * 48 + dw);
            i32x3 b2 = *(const i32x3*)(cur + (size_t)m2.z * 48 + dw);

            float wA = __int_as_float(m.y) * INV256;
            float wB = __int_as_float(m.w) * INV256;
            float fa[8], fb[8];
            unpack12((unsigned)a[0], (unsigned)a[1], (unsigned)a[2], fa);
            unpack12((unsigned)b[0], (unsigned)b[1], (unsigned)b[2], fb);
#pragma unroll
            for (int j = 0; j < 8; ++j)
                acc[j] = fmaf(wA, fa[j], fmaf(wB, fb[j], acc[j]));

            m = m2; a = a2; b = b2;
        }
        {   // tail window
            float wA = __int_as_float(m.y) * INV256;
            float wB = __int_as_float(m.w) * INV256;
            float fa[8], fb[8];
            unpack12((unsigned)a[0], (unsigned)a[1], (unsigned)a[2], fa);
            unpack12((unsigned)b[0], (unsigned)b[1], (unsigned)b[2], fb);
#pragma unroll
            for (int j = 0; j < 8; ++j)
                acc[j] = fmaf(wA, fa[j], fmaf(wB, fb[j], acc[j]));
        }

        // butterfly-combine the four group partials
#pragma unroll
        for (int j = 0; j < 8; ++j) {
            acc[j] += __shfl_xor(acc[j], 16);
            acc[j] += __shfl_xor(acc[j], 32);
        }

        if (lane < 16) {
            h16x8 hv = *(const h16x8*)(h0 + (size_t)i * 128 + sl * 8);
            float o[8];
#pragma unroll
            for (int j = 0; j < 8; ++j)
                o[j] = ALPHA_F * (float)hv[j] + (1.f - ALPHA_F) * acc[j];
            if (fout) {
                f32x4 o0, o1;
#pragma unroll
                for (int j = 0; j < 4; ++j) { o0[j] = o[j]; o1[j] = o[4 + j]; }
                *(f32x4*)(fout + (size_t)i * 128 + sl * 8)     = o0;
                *(f32x4*)(fout + (size_t)i * 128 + sl * 8 + 4) = o1;
            } else {
                unsigned d[3];
                pack12(o, d);
                unsigned* p = nxt + (size_t)i * 48 + dw;
                p[0] = d[0]; p[1] = d[1]; p[2] = d[2];
            }
        }
    }
}

// ---------------------------------------------------------------------------
static inline size_t align_up(size_t x) { return (x + 255) & ~(size_t)255; }

extern "C" void kernel_launch(void* const* d_in, const int* in_sizes, int n_in,
                              void* d_out, int out_size, void* d_ws, size_t ws_size,
                              hipStream_t stream)
{
    const float* x   = (const float*)d_in[0];
    const int*   ei  = (const int*)d_in[1];
    const float* W1  = (const float*)d_in[2];
    const float* b1  = (const float*)d_in[3];
    const float* g1  = (const float*)d_in[4];
    const float* be1 = (const float*)d_in[5];
    const float* m1  = (const float*)d_in[6];
    const float* v1  = (const float*)d_in[7];
    const float* W2  = (const float*)d_in[8];
    const float* b2  = (const float*)d_in[9];
    const float* g2  = (const float*)d_in[10];
    const float* be2 = (const float*)d_in[11];
    const float* m2  = (const float*)d_in[12];
    const float* v2  = (const float*)d_in[13];

    const int N = in_sizes[0] / 512;   // 50000
    const int E = in_sizes[1] / 2;     // 800000
    const int* src = ei;
    const int* dst = ei + E;
    const int CSR_CAP = E + 8 * N;     // int2 entries
    const int NB = (N + 1023) / 1024;  // 49

    char* ws = (char*)d_ws;
    size_t off = 0;
    _Float16* hAh = (_Float16*)(ws + off); off += align_up((size_t)N * 128 * 2);
    _Float16* h0h = (_Float16*)(ws + off); off += align_up((size_t)N * 128 * 2);
    unsigned* q0  = (unsigned*)(ws + off); off += align_up((size_t)N * 48 * 4);
    unsigned* q1  = (unsigned*)(ws + off); off += align_up((size_t)N * 48 * 4);
    unsigned* q2  = (unsigned*)(ws + off); off += align_up((size_t)N * 48 * 4);
    int*    deg  = (int*)(ws + off);    off += align_up((size_t)N * 4);
    float*  dinv = (float*)(ws + off);  off += align_up((size_t)N * 4);
    int*    offs = (int*)(ws + off);    off += align_up((size_t)(N + 1) * 4);
    int*    curs = (int*)(ws + off);    off += align_up((size_t)N * 4);
    int*    bsum = (int*)(ws + off);    off += align_up((size_t)256 * 4);
    int2*   csr  = (int2*)(ws + off);   off += align_up((size_t)CSR_CAP * 8);
    _Float16* w1s = (_Float16*)(ws + off); off += align_up((size_t)512 * 128 * 2);
    _Float16* w2s = (_Float16*)(ws + off); off += align_up((size_t)128 * 128 * 2);

    // --- graph preprocessing ---
    hipMemsetAsync(deg, 0, (size_t)N * 4, stream);
    count_deg<<<(E + 255) / 256, 256, 0, stream>>>(dst, E, deg);
    scan_block_sums<<<NB, 256, 0, stream>>>(deg, bsum, N);
    scan_offsets<<<NB, 256, 0, stream>>>(deg, bsum, offs, curs, dinv, N, NB);
    scatter_csr<<<(E + 255) / 256, 256, 0, stream>>>(src, dst, E, dinv, curs, csr);
    fill_self_pad<<<(N + 255) / 256, 256, 0, stream>>>(offs, deg, dinv, csr, N);

    // --- weights -> staging-interleaved fp16 ---
    convert_wstg<<<(512 * 128 + 255) / 256, 256, 0, stream>>>(W1, w1s, 512);
    convert_wstg<<<(128 * 128 + 255) / 256, 256, 0, stream>>>(W2, w2s, 128);

    // --- MLP: hAh = BN1(relu(x@W1+b1)) fp16; h0h = BN2(hAh@W2+b2) fp16 ---
    gemm_stage_bn<false, true><<<(N + 63) / 64, 256, 0, stream>>>(
        x, w1s, b1, g1, be1, m1, v1, hAh, N, 512, 1);
    gemm_stage_bn<true, true><<<(N + 63) / 64, 256, 0, stream>>>(
        hAh, w2s, b2, g2, be2, m2, v2, h0h, N, 128, 0);

    // --- pack h0 into 12-bit rows (initial cur) ---
    pack_rows<<<(N * 16 + 255) / 256, 256, 0, stream>>>(h0h, q0, N * 16);

    // --- 10 propagation steps (packed ping-pong); step 10 writes fp32 d_out ---
    const unsigned* cur = q0;
    for (int k = 0; k < 10; ++k) {
        unsigned* nxt = (k & 1) ? q2 : q1;
        float* fo = (k == 9) ? (float*)d_out : nullptr;
        appnp_step_q<<<NWAVES / 4, 256, 0, stream>>>(
            cur, h0h, offs, csr, nxt, fo, N);
        cur = nxt;
    }

    (void)n_in; (void)out_size; (void)ws_size;
}